// Round 11
// baseline (118.030 us; speedup 1.0000x reference)
//
#include <hip/hip_runtime.h>

// VectorQuantizer R10: input (16,64,64,64) f32 channel-first, codebook (1024,64) f32.
// out = [quantized (16,64,64,64) f32 | indices (16,64,64) as f32].
//
// Fused single kernel, codebook LDS-resident, ALL LDS traffic conflict-free:
//  - block = 512 thr / 8 waves / 256 tokens; wave = 32 tokens x full K.
//  - B: global float4 -> padded raw f32 LDS (16B-stride writes) -> per-lane
//    scalar fragment reads (2/bank) -> hi/lo f16 registers. No s_bf.
//  - A: 4 rotated K-quarter phases; fragment-ordered staging (thread<->frag,
//    lanes write consecutive v8h) -> hot loop pure ds_read_b128 @16B stride.
//  - esq: one hoisted exact-f32 pre-pass (coalesced + shfl reduce).
// Numerics IDENTICAL to R9 (absmax 0): 3-chain split-f16 (sigma ~6e-5),
// esq folded via (e_hi,e_lo) x ones-B MFMA, exact value+slot top-2 tracking,
// gap < EPS=2e-3 (33 sigma) -> block-cooperative exact fp32 rescan with
// ascending-k tie-break (exact ties always flagged => reference argmin).

typedef _Float16 v8h  __attribute__((ext_vector_type(8)));
typedef float    v16f __attribute__((ext_vector_type(16)));

constexpr int   D         = 64;
constexpr int   K         = 1024;
constexpr int   HW        = 4096;
constexpr int   DHW       = D * HW;
constexpr int   OUT_ELEMS = 16 * DHW;
constexpr float EPS       = 2e-3f;
constexpr int   RAWS      = 260;          // s_raw row stride (16B-aligned, bank-offset 4)

__global__ __launch_bounds__(512, 2) void vq_fused(
    const float* __restrict__ input,
    const float* __restrict__ codebook,
    float* __restrict__ out)
{
    // A frags: s_ch[tile][hl][kc][r][j] -> A[row=t*32+(r&31)][k=kc*16+(r>>5)*8+j]
    __shared__ _Float16 s_ch[8][2][4][64][8];   // 64 KB, current K-quarter, -2c hi/lo
    __shared__ float    s_raw[64][RAWS];        // 66.6 KB raw x tile (d-major, padded)
    __shared__ float    s_esq[K];               // 4 KB exact f32 e_sq
    __shared__ int      s_idx[256];
    __shared__ int      s_list[256];
    __shared__ int      s_cnt;
    __shared__ float    s_xf[64];
    __shared__ float    s_redv[8];
    __shared__ int      s_redk[8];

    const int tid  = threadIdx.x;
    const int lane = tid & 63;
    const int q    = __builtin_amdgcn_readfirstlane(tid >> 6);  // wave = token group
    const int lh   = lane >> 5;
    const int tok0 = blockIdx.x * 256;
    const int b    = tok0 >> 12;
    const int hwb  = tok0 & 4095;

    if (tid == 0) s_cnt = 0;

    // ---- B raw staging: coalesced float4 global -> conflict-free LDS ----
    {
        const float* xb = input + (size_t)b * DHW + hwb;
        #pragma unroll
        for (int pass = 0; pass < 8; ++pass) {
            const int g   = pass * 512 + tid;
            const int d   = g >> 6;                  // const per wave per pass
            const int hw4 = (g & 63) * 4;
            *(float4*)&s_raw[d][hw4] = *(const float4*)(xb + (size_t)d * HW + hw4);
        }
    }

    // ---- esq pre-pass: exact f32, coalesced read + shfl reduce (R9 pattern) ----
    #pragma unroll 4
    for (int p = 0; p < 32; ++p) {
        const int g  = p * 512 + tid;
        const int cw = g >> 4;
        const int dq = (g & 15) * 4;
        const float4 v = *(const float4*)(codebook + (size_t)cw * D + dq);
        float part = fmaf(v.x, v.x, fmaf(v.y, v.y, fmaf(v.z, v.z, v.w * v.w)));
        part += __shfl_xor(part, 1, 64);
        part += __shfl_xor(part, 2, 64);
        part += __shfl_xor(part, 4, 64);
        part += __shfl_xor(part, 8, 64);
        if ((tid & 15) == 0) s_esq[cw] = part;
    }
    __syncthreads();

    // ---- B fragments: per-lane scalar reads from s_raw (2/bank), hi/lo regs ----
    v8h bh[4], bl[4];
    {
        const int tok = q * 32 + (lane & 31);
        #pragma unroll
        for (int kc = 0; kc < 4; ++kc)
            #pragma unroll
            for (int j = 0; j < 8; ++j) {
                const float f = s_raw[kc * 16 + lh * 8 + j][tok];
                const _Float16 fh = (_Float16)f;
                bh[kc][j] = fh;
                bl[kc][j] = (_Float16)(f - (float)fh);
            }
    }

    v8h b5 = {};                       // ones at k=0,1 (pairs with esq fold)
    if (lh == 0) { b5[0] = (_Float16)1.0f; b5[1] = (_Float16)1.0f; }

    v16f Z = {0,0,0,0,0,0,0,0,0,0,0,0,0,0,0,0};
    const float INF = __builtin_huge_valf();
    float bv = INF, b2 = INF;
    int   sl = 0;

    #pragma unroll 1
    for (int p = 0; p < 4; ++p) {
        const int phR = (blockIdx.x + p) & 3;      // rotated K-quarter
        const int cw0 = phR * 256;

        // ---- A staging, fragment-ordered: conflict-free v8h writes ----
        #pragma unroll
        for (int pass = 0; pass < 4; ++pass) {
            const int F  = pass * 512 + tid;       // frag id in quarter [0,2048)
            const int r  = F & 63;                 // == lane (consecutive per wave)
            const int kc = (F >> 6) & 3;           // const per wave
            const int Tl = F >> 8;                 // const per wave
            const int cw = cw0 + Tl * 32 + (r & 31);
            const int d0 = kc * 16 + (r >> 5) * 8;
            const float4 u0 = *(const float4*)(codebook + (size_t)cw * D + d0);
            const float4 u1 = *(const float4*)(codebook + (size_t)cw * D + d0 + 4);
            const float vv[8] = {u0.x, u0.y, u0.z, u0.w, u1.x, u1.y, u1.z, u1.w};
            v8h hh, hl;
            #pragma unroll
            for (int j = 0; j < 8; ++j) {
                const float w = -2.0f * vv[j];
                const _Float16 wh = (_Float16)w;
                hh[j] = wh;
                hl[j] = (_Float16)(w - (float)wh);
            }
            *(v8h*)&s_ch[Tl][0][kc][r][0] = hh;
            *(v8h*)&s_ch[Tl][1][kc][r][0] = hl;
        }
        __syncthreads();

        // ---- compute 8 tiles from LDS: 13 MFMA each (R9-verified chain) ----
        #pragma unroll 1
        for (int t = 0; t < 8; ++t) {
            const int Tg = phR * 8 + t;
            float e = 0.0f;
            if (lane < 32) e = s_esq[cw0 + t * 32 + lane];
            v8h ae = {};
            const _Float16 eh = (_Float16)e;
            ae[0] = eh;
            ae[1] = (_Float16)(e - (float)eh);

            const v8h ah0 = *(const v8h*)&s_ch[t][0][0][lane][0];
            const v8h ah1 = *(const v8h*)&s_ch[t][0][1][lane][0];
            const v8h ah2 = *(const v8h*)&s_ch[t][0][2][lane][0];
            const v8h ah3 = *(const v8h*)&s_ch[t][0][3][lane][0];
            const v8h al0 = *(const v8h*)&s_ch[t][1][0][lane][0];
            const v8h al1 = *(const v8h*)&s_ch[t][1][1][lane][0];
            const v8h al2 = *(const v8h*)&s_ch[t][1][2][lane][0];
            const v8h al3 = *(const v8h*)&s_ch[t][1][3][lane][0];

            v16f accA = __builtin_amdgcn_mfma_f32_32x32x16_f16(ae,  b5,    Z,    0, 0, 0);
            v16f accB = __builtin_amdgcn_mfma_f32_32x32x16_f16(al0, bh[0], Z,    0, 0, 0);
            accA = __builtin_amdgcn_mfma_f32_32x32x16_f16(ah0, bh[0], accA, 0, 0, 0);
            accB = __builtin_amdgcn_mfma_f32_32x32x16_f16(al1, bh[1], accB, 0, 0, 0);
            accA = __builtin_amdgcn_mfma_f32_32x32x16_f16(ah1, bh[1], accA, 0, 0, 0);
            accB = __builtin_amdgcn_mfma_f32_32x32x16_f16(al2, bh[2], accB, 0, 0, 0);
            accA = __builtin_amdgcn_mfma_f32_32x32x16_f16(ah2, bh[2], accA, 0, 0, 0);
            accB = __builtin_amdgcn_mfma_f32_32x32x16_f16(al3, bh[3], accB, 0, 0, 0);
            accA = __builtin_amdgcn_mfma_f32_32x32x16_f16(ah3, bh[3], accA, 0, 0, 0);
            accB = __builtin_amdgcn_mfma_f32_32x32x16_f16(ah0, bl[0], accB, 0, 0, 0);
            accB = __builtin_amdgcn_mfma_f32_32x32x16_f16(ah1, bl[1], accB, 0, 0, 0);
            accB = __builtin_amdgcn_mfma_f32_32x32x16_f16(ah2, bl[2], accB, 0, 0, 0);
            accB = __builtin_amdgcn_mfma_f32_32x32x16_f16(ah3, bl[3], accB, 0, 0, 0);

            // exact value+slot top-2 tracking
            #pragma unroll
            for (int r = 0; r < 16; ++r) {
                const float s = accA[r] + accB[r];
                b2 = __builtin_amdgcn_fmed3f(s, bv, b2);
                if (s < bv) { bv = s; sl = (Tg << 4) | r; }
            }
        }
        __syncthreads();   // protect s_ch overwrite by next phase
    }

    // ---- cross-half-row merge (lane <-> lane^32), decode cw, flag near-ties ----
    {
        const float obv = __shfl_xor(bv, 32, 64);
        const float ob2 = __shfl_xor(b2, 32, 64);
        const int   osl = __shfl_xor(sl, 32, 64);
        const bool  oth = obv < bv;                 // strict: tie keeps lh=0's pick
        const float B1  = oth ? obv : bv;
        const float B2  = fminf(fmaxf(bv, obv), fminf(b2, ob2));
        const int   wsl = oth ? osl : sl;
        const int   wlh = oth ? (lh ^ 1) : lh;
        const int   r   = wsl & 15;
        const int   Tt  = wsl >> 4;                 // global tile 0..31
        const int   cw  = Tt * 32 + (r & 3) + 8 * (r >> 2) + 4 * wlh;
        if (lane < 32) {
            s_idx[q * 32 + lane] = cw;
            if (B2 - B1 < EPS) {
                const int pos = atomicAdd(&s_cnt, 1);
                s_list[pos] = q * 32 + lane;
            }
        }
    }
    __syncthreads();

    // ---- exact fp32 rescan, block-cooperative (rare: ~2e-4 of tokens) ----
    {
        const int cnt = s_cnt;
        const int rr  = tid >> 3;   // codeword row within 64-chunk, 0..63
        const int c   = tid & 7;    // d-octant (8 floats)
        for (int ii = 0; ii < cnt; ++ii) {
            const int tl = s_list[ii];
            if (tid < 64) s_xf[tid] = s_raw[tid][tl];
            __syncthreads();
            const float4* xs4 = (const float4*)&s_xf[c * 8];
            const float4 x0 = xs4[0], x1 = xs4[1];
            float bestv = INF; int bestk = K;
            #pragma unroll 4
            for (int i = 0; i < 16; ++i) {
                const int k = i * 64 + rr;               // ascending per thread
                const float4* c4 = (const float4*)(codebook + (size_t)k * D + c * 8);
                const float4 c0 = c4[0], c1 = c4[1];
                float p0 = 0.f, p1 = 0.f;
                p0 = fmaf(x0.x, c0.x, p0); p0 = fmaf(x0.y, c0.y, p0);
                p0 = fmaf(x0.z, c0.z, p0); p0 = fmaf(x0.w, c0.w, p0);
                p1 = fmaf(x1.x, c1.x, p1); p1 = fmaf(x1.y, c1.y, p1);
                p1 = fmaf(x1.z, c1.z, p1); p1 = fmaf(x1.w, c1.w, p1);
                float dp = p0 + p1;
                dp += __shfl_xor(dp, 1, 64);             // sum over 8 octants
                dp += __shfl_xor(dp, 2, 64);
                dp += __shfl_xor(dp, 4, 64);
                const float s = fmaf(-2.0f, dp, s_esq[k]);
                if (s < bestv) { bestv = s; bestk = k; }
            }
            #pragma unroll
            for (int off = 8; off <= 32; off <<= 1) {    // reduce rows within wave
                const float ov = __shfl_xor(bestv, off, 64);
                const int   ok = __shfl_xor(bestk, off, 64);
                if (ov < bestv || (ov == bestv && ok < bestk)) { bestv = ov; bestk = ok; }
            }
            if (lane == 0) { s_redv[q] = bestv; s_redk[q] = bestk; }
            __syncthreads();
            if (tid == 0) {
                float bb = s_redv[0]; int bk = s_redk[0];
                #pragma unroll
                for (int w = 1; w < 8; ++w) {
                    const float v = s_redv[w]; const int kk = s_redk[w];
                    if (v < bb || (v == bb && kk < bk)) { bb = v; bk = kk; }
                }
                s_idx[tl] = bk;
            }
            __syncthreads();
        }
    }

    // ---- epilogue: per-channel coalesced stores (thread = token x d-half) ----
    {
        const int token = tid & 255;
        const int dh    = tid >> 8;                      // 0/1
        const int idx   = s_idx[token];
        const float4* c4 = (const float4*)(codebook + (size_t)idx * D + dh * 32);
        float4 cr[8];
        #pragma unroll
        for (int j = 0; j < 8; ++j) cr[j] = c4[j];
        float* ob = out + (size_t)b * DHW + (size_t)dh * 32 * HW + hwb + token;
        #pragma unroll
        for (int j = 0; j < 8; ++j) {
            ob[(size_t)(4 * j + 0) * HW] = cr[j].x;
            ob[(size_t)(4 * j + 1) * HW] = cr[j].y;
            ob[(size_t)(4 * j + 2) * HW] = cr[j].z;
            ob[(size_t)(4 * j + 3) * HW] = cr[j].w;
        }
        if (tid < 256) out[OUT_ELEMS + tok0 + tid] = (float)s_idx[tid];
    }
}

extern "C" void kernel_launch(void* const* d_in, const int* in_sizes, int n_in,
                              void* d_out, int out_size, void* d_ws, size_t ws_size,
                              hipStream_t stream) {
    const float* input    = (const float*)d_in[0];
    const float* codebook = (const float*)d_in[1];
    float* out            = (float*)d_out;
    vq_fused<<<256, 512, 0, stream>>>(input, codebook, out);
}